// Round 15
// baseline (714.339 us; speedup 1.0000x reference)
//
#include <hip/hip_runtime.h>
#include <hip/hip_bf16.h>
#include <cstdint>
#include <cstddef>

#define NN 50000     // nodes
#define EE 1000000   // edges
#define NB 2         // batch
#define OUT_ELEMS (NB * NN * 64 + NB * NN * 4)   // 6,800,000 floats

#define MSTR 72      // tile stride (shorts): 144 B rows; cols 0..63 = m, 64..71 spare
#define TILE (32 * MSTR)   // one batch m-tile, shorts (2304)

// packed-weight layout (shorts): B-fragment order [kstep][ntile][lane][8]
#define P_E1 0
#define P_E2 10240
#define P_C1 14336
#define P_F1 18432
#define P_F2 26624
#define E1_MAIN_SHORTS 8192      // e1 s=0..3 staged to LDS (16,384 B)

// d_ws byte offsets
#define WS_CNT   0            // int[NN]
#define WS_OFF   200704       // int[NN+1]
#define WS_CUR   401408       // int[NN]
#define WS_PART  602112       // int[256] scan partials
#define WS_ECS   603136       // int4[EE]  (16 MB)
#define WS_PK    16603136     // short[30720]
#define WS_HB    16664576     // short[NB*NN*64]  (12.8 MB)
#define WS_LIN   29464576     // short8[EE] lin streams (16 MB)

#define EDGE_BLOCKS 768
#define TOTWAVE (EDGE_BLOCKS * 4)     // 3072
#define NWIN (EE / 32)                // 31250 windows
#define NPART 196                      // scan blocks: 196*256 >= NN

typedef __attribute__((ext_vector_type(8))) short short8;
typedef __attribute__((ext_vector_type(4))) float f32x4;

__device__ __forceinline__ float fast_rcp(float v) { return __builtin_amdgcn_rcpf(v); }
__device__ __forceinline__ float silu_f(float v) { return v * fast_rcp(1.0f + __expf(-v)); }
__device__ __forceinline__ float ssgn_f(float v) { return v * fast_rcp(1.0f + fabsf(v)); }

__device__ __forceinline__ short f2bf(float f) {
    __hip_bfloat16 h = __float2bfloat16(f);
    return *reinterpret_cast<short*>(&h);
}
__device__ __forceinline__ float bf2f(short s) {
    union { unsigned u; float f; } c; c.u = ((unsigned)(unsigned short)s) << 16; return c.f;
}
__device__ __forceinline__ short8 pack8(float4 a, float4 b) {
    short8 r;
    r[0] = f2bf(a.x); r[1] = f2bf(a.y); r[2] = f2bf(a.z); r[3] = f2bf(a.w);
    r[4] = f2bf(b.x); r[5] = f2bf(b.y); r[6] = f2bf(b.z); r[7] = f2bf(b.w);
    return r;
}

// ---------------------------------------------------------------------------
// Fused prep: conv_h | pack_weights | hist | zero d_out
// ---------------------------------------------------------------------------
#define PREP_CONV 3125
#define PREP_PACK 15
#define PREP_HIST 3907
#define PREP_ZERO 3321

__global__ void prep_kernel(const float* __restrict__ h, short* __restrict__ hb16,
                            const float* __restrict__ w_e1, const float* __restrict__ w_e2,
                            const float* __restrict__ w_c1, const float* __restrict__ w_f1,
                            const float* __restrict__ w_f2, short* __restrict__ pk,
                            const int* __restrict__ ei, int* __restrict__ cnt_i,
                            float* __restrict__ out)
{
    const int bid = blockIdx.x;
    if (bid < PREP_CONV) {
        size_t i = ((size_t)bid * 256 + threadIdx.x) * 8;
        float4 lo = *reinterpret_cast<const float4*>(h + i);
        float4 hi = *reinterpret_cast<const float4*>(h + i + 4);
        *reinterpret_cast<short8*>(hb16 + i) = pack8(lo, hi);
    } else if (bid < PREP_CONV + PREP_PACK) {
        int g = (bid - PREP_CONV) * 256 + threadIdx.x;
        const int G_E1 = 5 * 4 * 64, G_E2 = 2 * 4 * 64, G_C1 = 2 * 4 * 64;
        const int G_F1 = 4 * 4 * 64, G_F2 = 2 * 4 * 64;
        if (g >= G_E1 + G_E2 + G_C1 + G_F1 + G_F2) return;
        const float* W; int loc; int mat;
        if (g < G_E1)                        { W = w_e1; loc = g;                         mat = 0; }
        else if (g < G_E1+G_E2)              { W = w_e2; loc = g - G_E1;                  mat = 1; }
        else if (g < G_E1+G_E2+G_C1)         { W = w_c1; loc = g - G_E1 - G_E2;           mat = 2; }
        else if (g < G_E1+G_E2+G_C1+G_F1)    { W = w_f1; loc = g - G_E1 - G_E2 - G_C1;    mat = 3; }
        else                                 { W = w_f2; loc = g - G_E1-G_E2-G_C1-G_F1;   mat = 4; }
        int l = loc & 63, n = (loc >> 6) & 3, s = loc >> 8;
        short8 out8;
        #pragma unroll
        for (int j = 0; j < 8; j++) {
            int kp = s * 32 + ((l >> 4) * 8) + j;
            int ko; bool valid;
            if (mat == 0) {
                if (kp < 128)      { ko = kp;     valid = true; }
                else if (kp < 144) { ko = kp + 1; valid = true; }   // ea rows (orig 129..144)
                else if (kp == 144){ ko = 128;    valid = true; }   // radial row
                else               { ko = 0;      valid = false; }
            } else if (mat == 3) { ko = kp; valid = kp < 128; }
            else                 { ko = kp; valid = kp < 64; }
            float v = valid ? W[ko * 64 + (n * 16 + (l & 15))] : 0.0f;
            out8[j] = f2bf(v);
        }
        *reinterpret_cast<short8*>(pk + (size_t)g * 8) = out8;
    } else if (bid < PREP_CONV + PREP_PACK + PREP_HIST) {
        int e = (bid - PREP_CONV - PREP_PACK) * 256 + threadIdx.x;
        if (e < EE) atomicAdd(&cnt_i[ei[e]], 1);
    } else {
        size_t i = ((size_t)(bid - PREP_CONV - PREP_PACK - PREP_HIST) * 256 + threadIdx.x) * 8;
        if (i < OUT_ELEMS) {
            float4 z = float4{0, 0, 0, 0};
            *reinterpret_cast<float4*>(out + i)     = z;
            *reinterpret_cast<float4*>(out + i + 4) = z;
        }
    }
}

// ---------------------------------------------------------------------------
// Multi-block exclusive scan of cnt -> off/cur (3 small dispatches)
// ---------------------------------------------------------------------------
__global__ void scanA(const int* __restrict__ cnt_i, int* __restrict__ part) {
    int i = blockIdx.x * 256 + threadIdx.x;
    int v = (i < NN) ? cnt_i[i] : 0;
    #pragma unroll
    for (int d = 1; d < 64; d <<= 1) v += __shfl_xor(v, d);
    __shared__ int red[4];
    if ((threadIdx.x & 63) == 0) red[threadIdx.x >> 6] = v;
    __syncthreads();
    if (threadIdx.x == 0) part[blockIdx.x] = red[0] + red[1] + red[2] + red[3];
}

__global__ void scanB(int* __restrict__ part) {
    __shared__ int s[256];
    int t = threadIdx.x;
    int v = (t < NPART) ? part[t] : 0;
    s[t] = v;
    __syncthreads();
    for (int d = 1; d < 256; d <<= 1) {
        int u = (t >= d) ? s[t - d] : 0;
        __syncthreads();
        s[t] += u;
        __syncthreads();
    }
    if (t < NPART) part[t] = s[t] - v;   // exclusive
}

__global__ void scanC(const int* __restrict__ cnt_i, const int* __restrict__ part,
                      int* __restrict__ off, int* __restrict__ cur) {
    __shared__ int s[256];
    int i = blockIdx.x * 256 + threadIdx.x;
    int t = threadIdx.x;
    int v = (i < NN) ? cnt_i[i] : 0;
    s[t] = v;
    __syncthreads();
    for (int d = 1; d < 256; d <<= 1) {
        int u = (t >= d) ? s[t - d] : 0;
        __syncthreads();
        s[t] += u;
        __syncthreads();
    }
    int excl = s[t] - v + part[blockIdx.x];
    if (i < NN) { off[i] = excl; cur[i] = excl; }
    if (i == 0) off[NN] = EE;
}

// ---------------------------------------------------------------------------
// scatter: emits {eid,row,col,radpair} + lin streams per sorted position.
// ---------------------------------------------------------------------------
__global__ void scatter_kernel(const int* __restrict__ ei, const float* __restrict__ x,
                               const float* __restrict__ sm_p, const float* __restrict__ om_p,
                               int* __restrict__ cur, int4* __restrict__ ecs,
                               short* __restrict__ lins) {
    int e = blockIdx.x * 256 + threadIdx.x;
    if (e >= EE) return;
    int r = ei[e], c = ei[EE + e];
    int p = atomicAdd(&cur[r], 1);
    const float smv = sm_p[0], omv = om_p[0];
    short rp[2];
    short8 lv;
    #pragma unroll
    for (int b = 0; b < 2; b++) {
        float4 xr = *reinterpret_cast<const float4*>(x + ((size_t)b * NN + r) * 4);
        float4 xc = *reinterpret_cast<const float4*>(x + ((size_t)b * NN + c) * 4);
        float d0 = xr.x - xc.x, d1 = xr.y - xc.y, d2 = xr.z - xc.z, d3 = xr.w - xc.w;
        rp[b] = f2bf(d1 * d1 + d2 * d2 + d3 * d3 - d0 * d0);
        lv[b * 4 + 0] = f2bf(smv * xr.x + omv * xc.x);
        lv[b * 4 + 1] = f2bf(smv * xr.y + omv * xc.y);
        lv[b * 4 + 2] = f2bf(smv * xr.z + omv * xc.z);
        lv[b * 4 + 3] = f2bf(smv * xr.w + omv * xc.w);
    }
    int radpair = (int)(unsigned short)rp[0] | ((int)(unsigned short)rp[1] << 16);
    ecs[p] = make_int4(e, r, c, radpair);
    *reinterpret_cast<short8*>(lins + (size_t)p * 8) = lv;
}

// ---------------------------------------------------------------------------
// Edge kernel: PERSISTENT. 768 blocks x 4 waves; each wave owns a contiguous
// chunk of ~10 sorted 32-edge windows (both batches). Cross-window software
// pipeline: window w+1's idx+gathers issue before window w's GEMM2/3+scatter.
// ---------------------------------------------------------------------------
__global__ __launch_bounds__(256, 3) void edge_kernel(
    const short* __restrict__ hb16,
    const float* __restrict__ ea, const int4* __restrict__ ecs,
    const short* __restrict__ lins,
    const float* __restrict__ b_e1, const float* __restrict__ b_e2,
    const float* __restrict__ b_c1, const float* __restrict__ w_c2,
    const short* __restrict__ pk,
    float* __restrict__ agg, float* __restrict__ xagg)
{
    __shared__ short wlds[E1_MAIN_SHORTS];   // 16,384 B: e1 s=0..3 B-frags
    __shared__ short smem[4][2 * TILE];      // 36,864 B
    const int wid  = threadIdx.x >> 6;
    const int lane = threadIdx.x & 63;
    short* sm  = smem[wid];
    float* smf = reinterpret_cast<float*>(sm);

    // ---- stage e1 main weights to LDS (once per persistent block) ----
    {
        short8* dst = reinterpret_cast<short8*>(wlds);
        const short8* src = reinterpret_cast<const short8*>(pk);
        #pragma unroll
        for (int i = 0; i < E1_MAIN_SHORTS / 8 / 256; i++)
            dst[i * 256 + threadIdx.x] = src[i * 256 + threadIdx.x];
    }
    __syncthreads();

    // XCD swizzle (768 % 8 == 0): same-XCD blocks get contiguous window chunks
    const int bswz = (blockIdx.x & 7) * (EDGE_BLOCKS / 8) + (blockIdx.x >> 3);
    const int gwave = bswz * 4 + wid;
    const int wbeg = (int)(((long long)gwave * NWIN) / TOTWAVE);
    const int wend = (int)(((long long)(gwave + 1) * NWIN) / TOTWAVE);

    const int l15 = lane & 15;
    const int gq  = lane >> 4;
    const int kg  = gq * 8;

    const short* hbb[2] = { hb16, hb16 + (size_t)NN * 64 };
    const short8* pke1L = reinterpret_cast<const short8*>(wlds);       // s=0..3 (LDS)
    const short8* pke1G = reinterpret_cast<const short8*>(pk + P_E1);  // s=4 tail (global, L1-hot)
    const short8* pke2  = reinterpret_cast<const short8*>(pk + P_E2);
    const short8* pkc1  = reinterpret_cast<const short8*>(pk + P_C1);

    float wc2v[4];
    #pragma unroll
    for (int n = 0; n < 4; n++) wc2v[n] = w_c2[n * 16 + l15];

    // ---- pipeline state for CURRENT window ----
    int4 ecC = make_int4(0, 0, 0, 0);
    short8 lvC = short8{0, 0, 0, 0, 0, 0, 0, 0};
    int rowmC[2], colmC[2], radpmC[2];
    short8 rowfC[2][2][2];   // [s][b][m]
    short8 colfC[2][2][2];   // [s2][b][m]
    float4 ealoC[2][2], eahiC[2][2];   // [b][m], valid for gq<2

    // ---- prologue: full prefetch of window wbeg ----
    {
        if (lane < 32) {
            ecC = ecs[(size_t)wbeg * 32 + lane];
            lvC = *reinterpret_cast<const short8*>(lins + ((size_t)wbeg * 32 + lane) * 8);
        }
        #pragma unroll
        for (int m = 0; m < 2; m++) {
            int src = m * 16 + l15;
            rowmC[m]  = __shfl(ecC.y, src);
            colmC[m]  = __shfl(ecC.z, src);
            radpmC[m] = __shfl(ecC.w, src);
        }
        int eidmP[2];
        #pragma unroll
        for (int m = 0; m < 2; m++) eidmP[m] = __shfl(ecC.x, m * 16 + l15);
        #pragma unroll
        for (int s = 0; s < 2; s++)
            #pragma unroll
            for (int b = 0; b < 2; b++)
                #pragma unroll
                for (int m = 0; m < 2; m++) {
                    rowfC[s][b][m] = *reinterpret_cast<const short8*>(
                        hbb[b] + (size_t)rowmC[m] * 64 + s * 32 + kg);
                    colfC[s][b][m] = *reinterpret_cast<const short8*>(
                        hbb[b] + (size_t)colmC[m] * 64 + s * 32 + kg);
                }
        if (gq < 2) {
            #pragma unroll
            for (int b = 0; b < 2; b++)
                #pragma unroll
                for (int m = 0; m < 2; m++) {
                    const float* src = ea + ((size_t)b * EE + eidmP[m]) * 16 + gq * 8;
                    ealoC[b][m] = *reinterpret_cast<const float4*>(src);
                    eahiC[b][m] = *reinterpret_cast<const float4*>(src + 4);
                }
        }
    }

    #pragma unroll 1
    for (int w = wbeg; w < wend; w++) {
        const bool hasN = (w + 1 < wend);

        // ---- prefetch next window's idx/lin streams (coalesced) ----
        int4 ecN = make_int4(0, 0, 0, 0);
        short8 lvN = short8{0, 0, 0, 0, 0, 0, 0, 0};
        if (hasN && lane < 32) {
            ecN = ecs[(size_t)(w + 1) * 32 + lane];
            lvN = *reinterpret_cast<const short8*>(lins + ((size_t)(w + 1) * 32 + lane) * 8);
        }

        // ---- build tail fragments from prefetched ea/radial ----
        short8 tail[2][2];
        #pragma unroll
        for (int b = 0; b < 2; b++)
            #pragma unroll
            for (int m = 0; m < 2; m++) {
                short8 v = short8{0, 0, 0, 0, 0, 0, 0, 0};
                if (gq < 2) {
                    v = pack8(ealoC[b][m], eahiC[b][m]);
                } else if (gq == 2) {
                    v[0] = (short)((b == 0) ? (radpmC[m] & 0xffff)
                                            : ((unsigned)radpmC[m] >> 16));
                }
                tail[b][m] = v;
            }

        // ---- GEMM1: all A-fragments prefetched ----
        f32x4 acc[2][2][4];
        #pragma unroll
        for (int n = 0; n < 4; n++) {
            float bias = b_e1[n * 16 + l15];
            #pragma unroll
            for (int b = 0; b < 2; b++)
                #pragma unroll
                for (int m = 0; m < 2; m++) acc[b][m][n] = f32x4{bias, bias, bias, bias};
        }
        __builtin_amdgcn_s_setprio(1);
        #pragma unroll
        for (int n = 0; n < 4; n++) {
            short8 bfr = pke1G[(4 * 4 + n) * 64 + lane];
            #pragma unroll
            for (int b = 0; b < 2; b++)
                #pragma unroll
                for (int m = 0; m < 2; m++)
                    acc[b][m][n] = __builtin_amdgcn_mfma_f32_16x16x32_bf16(tail[b][m], bfr, acc[b][m][n], 0, 0, 0);
        }
        #pragma unroll
        for (int s = 0; s < 2; s++)
            #pragma unroll
            for (int n = 0; n < 4; n++) {
                short8 bfr = pke1L[(s * 4 + n) * 64 + lane];
                #pragma unroll
                for (int b = 0; b < 2; b++)
                    #pragma unroll
                    for (int m = 0; m < 2; m++)
                        acc[b][m][n] = __builtin_amdgcn_mfma_f32_16x16x32_bf16(rowfC[s][b][m], bfr, acc[b][m][n], 0, 0, 0);
            }
        #pragma unroll
        for (int s2 = 0; s2 < 2; s2++)
            #pragma unroll
            for (int n = 0; n < 4; n++) {
                short8 bfr = pke1L[((2 + s2) * 4 + n) * 64 + lane];
                #pragma unroll
                for (int b = 0; b < 2; b++)
                    #pragma unroll
                    for (int m = 0; m < 2; m++)
                        acc[b][m][n] = __builtin_amdgcn_mfma_f32_16x16x32_bf16(colfC[s2][b][m], bfr, acc[b][m][n], 0, 0, 0);
            }
        __builtin_amdgcn_s_setprio(0);

        // ---- derive next window + ISSUE its gathers (hide under GEMM2/3) ----
        int rowmN[2] = {0, 0}, colmN[2] = {0, 0}, radpmN[2] = {0, 0};
        short8 rowfN[2][2][2], colfN[2][2][2];
        float4 ealoN[2][2], eahiN[2][2];
        if (hasN) {
            int eidmN[2];
            #pragma unroll
            for (int m = 0; m < 2; m++) {
                int src = m * 16 + l15;
                rowmN[m]  = __shfl(ecN.y, src);
                colmN[m]  = __shfl(ecN.z, src);
                radpmN[m] = __shfl(ecN.w, src);
                eidmN[m]  = __shfl(ecN.x, src);
            }
            #pragma unroll
            for (int s = 0; s < 2; s++)
                #pragma unroll
                for (int b = 0; b < 2; b++)
                    #pragma unroll
                    for (int m = 0; m < 2; m++) {
                        rowfN[s][b][m] = *reinterpret_cast<const short8*>(
                            hbb[b] + (size_t)rowmN[m] * 64 + s * 32 + kg);
                        colfN[s][b][m] = *reinterpret_cast<const short8*>(
                            hbb[b] + (size_t)colmN[m] * 64 + s * 32 + kg);
                    }
            if (gq < 2) {
                #pragma unroll
                for (int b = 0; b < 2; b++)
                    #pragma unroll
                    for (int m = 0; m < 2; m++) {
                        const float* src = ea + ((size_t)b * EE + eidmN[m]) * 16 + gq * 8;
                        ealoN[b][m] = *reinterpret_cast<const float4*>(src);
                        eahiN[b][m] = *reinterpret_cast<const float4*>(src + 4);
                    }
            }
        }

        // ---- t1 = silu(acc) -> LDS (both batch tiles) ----
        #pragma unroll
        for (int b = 0; b < 2; b++)
            #pragma unroll
            for (int m = 0; m < 2; m++)
                #pragma unroll
                for (int n = 0; n < 4; n++)
                    #pragma unroll
                    for (int r = 0; r < 4; r++)
                        sm[b * TILE + (m * 16 + gq * 4 + r) * MSTR + n * 16 + l15] =
                            f2bf(silu_f(acc[b][m][n][r]));
        asm volatile("s_waitcnt lgkmcnt(0)" ::: "memory");

        // ---- GEMM2 ----
        f32x4 acc2[2][2][4];
        #pragma unroll
        for (int n = 0; n < 4; n++) {
            float bias = b_e2[n * 16 + l15];
            #pragma unroll
            for (int b = 0; b < 2; b++)
                #pragma unroll
                for (int m = 0; m < 2; m++) acc2[b][m][n] = f32x4{bias, bias, bias, bias};
        }
        #pragma unroll
        for (int s = 0; s < 2; s++) {
            short8 afr[2][2];
            #pragma unroll
            for (int b = 0; b < 2; b++)
                #pragma unroll
                for (int m = 0; m < 2; m++)
                    afr[b][m] = *reinterpret_cast<const short8*>(
                        sm + b * TILE + (m * 16 + l15) * MSTR + s * 32 + kg);
            __builtin_amdgcn_s_setprio(1);
            #pragma unroll
            for (int n = 0; n < 4; n++) {
                short8 bfr = pke2[(s * 4 + n) * 64 + lane];
                #pragma unroll
                for (int b = 0; b < 2; b++)
                    #pragma unroll
                    for (int m = 0; m < 2; m++)
                        acc2[b][m][n] = __builtin_amdgcn_mfma_f32_16x16x32_bf16(afr[b][m], bfr, acc2[b][m][n], 0, 0, 0);
            }
            __builtin_amdgcn_s_setprio(0);
        }
        asm volatile("s_waitcnt lgkmcnt(0)" ::: "memory");

        // ---- m = softsign(acc2) -> LDS ----
        #pragma unroll
        for (int b = 0; b < 2; b++)
            #pragma unroll
            for (int m = 0; m < 2; m++)
                #pragma unroll
                for (int n = 0; n < 4; n++)
                    #pragma unroll
                    for (int r = 0; r < 4; r++)
                        sm[b * TILE + (m * 16 + gq * 4 + r) * MSTR + n * 16 + l15] =
                            f2bf(ssgn_f(acc2[b][m][n][r]));
        asm volatile("s_waitcnt lgkmcnt(0)" ::: "memory");

        // ---- GEMM3 + phi ----
        f32x4 acc3[2][2][4];
        #pragma unroll
        for (int n = 0; n < 4; n++) {
            float bias = b_c1[n * 16 + l15];
            #pragma unroll
            for (int b = 0; b < 2; b++)
                #pragma unroll
                for (int m = 0; m < 2; m++) acc3[b][m][n] = f32x4{bias, bias, bias, bias};
        }
        #pragma unroll
        for (int s = 0; s < 2; s++) {
            short8 afr[2][2];
            #pragma unroll
            for (int b = 0; b < 2; b++)
                #pragma unroll
                for (int m = 0; m < 2; m++)
                    afr[b][m] = *reinterpret_cast<const short8*>(
                        sm + b * TILE + (m * 16 + l15) * MSTR + s * 32 + kg);
            __builtin_amdgcn_s_setprio(1);
            #pragma unroll
            for (int n = 0; n < 4; n++) {
                short8 bfr = pkc1[(s * 4 + n) * 64 + lane];
                #pragma unroll
                for (int b = 0; b < 2; b++)
                    #pragma unroll
                    for (int m = 0; m < 2; m++)
                        acc3[b][m][n] = __builtin_amdgcn_mfma_f32_16x16x32_bf16(afr[b][m], bfr, acc3[b][m][n], 0, 0, 0);
            }
            __builtin_amdgcn_s_setprio(0);
        }
        #pragma unroll
        for (int b = 0; b < 2; b++)
            #pragma unroll
            for (int m = 0; m < 2; m++)
                #pragma unroll
                for (int r = 0; r < 4; r++) {
                    float v = 0.0f;
                    #pragma unroll
                    for (int n = 0; n < 4; n++) v = fmaf(silu_f(acc3[b][m][n][r]), wc2v[n], v);
                    v += __shfl_xor(v, 1); v += __shfl_xor(v, 2);
                    v += __shfl_xor(v, 4); v += __shfl_xor(v, 8);
                    if (l15 == 0) smf[b * (TILE / 2) + (m * 16 + gq * 4 + r) * 36 + 32] = v;
                }
        asm volatile("s_waitcnt lgkmcnt(0)" ::: "memory");

        // ---- weighted coordinates = lin * phi ----
        if (lane < 32) {
            float phi0 = smf[lane * 36 + 32];
            float phi1 = smf[(TILE / 2) + lane * 36 + 32];
            float4 wv0, wv1;
            wv0.x = bf2f(lvC[0]) * phi0; wv0.y = bf2f(lvC[1]) * phi0;
            wv0.z = bf2f(lvC[2]) * phi0; wv0.w = bf2f(lvC[3]) * phi0;
            wv1.x = bf2f(lvC[4]) * phi1; wv1.y = bf2f(lvC[5]) * phi1;
            wv1.z = bf2f(lvC[6]) * phi1; wv1.w = bf2f(lvC[7]) * phi1;
            *reinterpret_cast<float4*>(smf + lane * 36 + 32) = wv0;
            *reinterpret_cast<float4*>(smf + (TILE / 2) + lane * 36 + 32) = wv1;
        }
        asm volatile("s_waitcnt lgkmcnt(0)" ::: "memory");

        // ---- shared ballot run-merged scatter over 32 edges, both batches ----
        const int rowHere = ecC.y;
        int nrow = __shfl_down(rowHere, 1);
        unsigned long long bmask = __ballot((lane == 31) || (lane < 31 && rowHere != nrow));
        float* aggb0 = agg;
        float* aggb1 = agg + (size_t)NN * 64;
        float* xb    = xagg + (size_t)((lane >> 2) & 1) * NN * 4;
        const int xsel = ((lane >> 2) & 1) * (TILE / 2) + (lane & 3);
        float mv0 = 0.0f, mv1 = 0.0f, xv = 0.0f;
        #pragma unroll
        for (int e = 0; e < 32; e++) {
            mv0 += bf2f(sm[e * MSTR + lane]);
            mv1 += bf2f(sm[TILE + e * MSTR + lane]);
            float t = smf[e * 36 + 32 + xsel];
            xv += (lane < 8) ? t : 0.0f;
            if ((bmask >> e) & 1ull) {
                int re = __shfl(rowHere, e);
                atomicAdd(aggb0 + (size_t)re * 64 + lane, mv0);
                atomicAdd(aggb1 + (size_t)re * 64 + lane, mv1);
                if (lane < 8) atomicAdd(xb + (size_t)re * 4 + (lane & 3), xv);
                mv0 = 0.0f; mv1 = 0.0f; xv = 0.0f;
            }
        }
        asm volatile("s_waitcnt lgkmcnt(0)" ::: "memory");

        // ---- rotate pipeline state ----
        if (hasN) {
            ecC = ecN; lvC = lvN;
            #pragma unroll
            for (int m = 0; m < 2; m++) {
                rowmC[m] = rowmN[m]; colmC[m] = colmN[m]; radpmC[m] = radpmN[m];
            }
            #pragma unroll
            for (int s = 0; s < 2; s++)
                #pragma unroll
                for (int b = 0; b < 2; b++)
                    #pragma unroll
                    for (int m = 0; m < 2; m++) {
                        rowfC[s][b][m] = rowfN[s][b][m];
                        colfC[s][b][m] = colfN[s][b][m];
                    }
            #pragma unroll
            for (int b = 0; b < 2; b++)
                #pragma unroll
                for (int m = 0; m < 2; m++) {
                    ealoC[b][m] = ealoN[b][m];
                    eahiC[b][m] = eahiN[b][m];
                }
        }
    }
}

// ---------------------------------------------------------------------------
// Node kernel: M=32 tiles
// ---------------------------------------------------------------------------
__global__ __launch_bounds__(256, 4) void node_kernel(
    const short* __restrict__ hb16, const float* __restrict__ x,
    const float* __restrict__ b_f1, const float* __restrict__ b_f2,
    const short* __restrict__ pk,
    const int* __restrict__ off,
    float* out_h, float* out_x)
{
    __shared__ short smem[4][32 * MSTR];
    const int wid  = threadIdx.x >> 6;
    const int lane = threadIdx.x & 63;
    short* sm = smem[wid];

    const int WN = (NN + 31) / 32;   // 1563
    const int gw = blockIdx.x * 4 + wid;
    if (gw >= NB * WN) return;
    const int b  = gw / WN;
    const int n0 = (gw - b * WN) * 32;

    const int l15 = lane & 15;
    const int gq  = lane >> 4;
    const int kg  = gq * 8;

    const short* hbb  = hb16 + (size_t)b * NN * 64;
    const float* aggb = out_h + (size_t)b * NN * 64;

    f32x4 acc[2][4];
    #pragma unroll
    for (int n = 0; n < 4; n++) {
        float bias = b_f1[n * 16 + l15];
        #pragma unroll
        for (int m = 0; m < 2; m++) acc[m][n] = f32x4{bias, bias, bias, bias};
    }
    const short8* pkf1 = reinterpret_cast<const short8*>(pk + P_F1);
    #pragma unroll
    for (int s = 0; s < 4; s++) {
        short8 afr[2];
        #pragma unroll
        for (int m = 0; m < 2; m++) {
            int nd = n0 + m * 16 + l15;
            if (nd >= NN) nd = NN - 1;
            if (s < 2) {
                afr[m] = *reinterpret_cast<const short8*>(
                    hbb + (size_t)nd * 64 + s * 32 + kg);
            } else {
                const float* base = aggb + (size_t)nd * 64 + (s & 1) * 32 + kg;
                float4 lo = *reinterpret_cast<const float4*>(base);
                float4 hi = *reinterpret_cast<const float4*>(base + 4);
                afr[m] = pack8(lo, hi);
            }
        }
        __builtin_amdgcn_s_setprio(1);
        #pragma unroll
        for (int n = 0; n < 4; n++) {
            short8 bfr = pkf1[(s * 4 + n) * 64 + lane];
            #pragma unroll
            for (int m = 0; m < 2; m++)
                acc[m][n] = __builtin_amdgcn_mfma_f32_16x16x32_bf16(afr[m], bfr, acc[m][n], 0, 0, 0);
        }
        __builtin_amdgcn_s_setprio(0);
    }

    #pragma unroll
    for (int m = 0; m < 2; m++)
        #pragma unroll
        for (int n = 0; n < 4; n++)
            #pragma unroll
            for (int r = 0; r < 4; r++)
                sm[(m * 16 + gq * 4 + r) * MSTR + n * 16 + l15] = f2bf(silu_f(acc[m][n][r]));
    asm volatile("s_waitcnt lgkmcnt(0)" ::: "memory");

    f32x4 acc2[2][4];
    #pragma unroll
    for (int n = 0; n < 4; n++) {
        float bias = b_f2[n * 16 + l15];
        #pragma unroll
        for (int m = 0; m < 2; m++) acc2[m][n] = f32x4{bias, bias, bias, bias};
    }
    const short8* pkf2 = reinterpret_cast<const short8*>(pk + P_F2);
    #pragma unroll
    for (int s = 0; s < 2; s++) {
        short8 afr[2];
        #pragma unroll
        for (int m = 0; m < 2; m++)
            afr[m] = *reinterpret_cast<const short8*>(sm + (m * 16 + l15) * MSTR + s * 32 + kg);
        __builtin_amdgcn_s_setprio(1);
        #pragma unroll
        for (int n = 0; n < 4; n++) {
            short8 bfr = pkf2[(s * 4 + n) * 64 + lane];
            #pragma unroll
            for (int m = 0; m < 2; m++)
                acc2[m][n] = __builtin_amdgcn_mfma_f32_16x16x32_bf16(afr[m], bfr, acc2[m][n], 0, 0, 0);
        }
        __builtin_amdgcn_s_setprio(0);
    }

    float* ohb = out_h + (size_t)b * NN * 64;
    #pragma unroll
    for (int m = 0; m < 2; m++)
        #pragma unroll
        for (int r = 0; r < 4; r++) {
            int nd = n0 + m * 16 + gq * 4 + r;
            if (nd < NN) {
                #pragma unroll
                for (int n = 0; n < 4; n++)
                    ohb[(size_t)nd * 64 + n * 16 + l15] = ssgn_f(acc2[m][n][r]);
            }
        }

    const int node = n0 + lane;
    if (lane < 32 && node < NN) {
        int c_i = off[node + 1] - off[node];
        float c = (float)(c_i < 1 ? 1 : c_i);
        float invc = fast_rcp(c);
        const float4 xv = *reinterpret_cast<const float4*>(x + ((size_t)b * NN + node) * 4);
        float* xop = out_x + ((size_t)b * NN + node) * 4;
        float4 xa = *reinterpret_cast<float4*>(xop);
        float4 r;
        r.x = xv.x + xa.x * invc;
        r.y = xv.y + xa.y * invc;
        r.z = xv.z + xa.z * invc;
        r.w = xv.w + xa.w * invc;
        *reinterpret_cast<float4*>(xop) = r;
    }
}

// ---------------------------------------------------------------------------
extern "C" void kernel_launch(void* const* d_in, const int* in_sizes, int n_in,
                              void* d_out, int out_size, void* d_ws, size_t ws_size,
                              hipStream_t stream) {
    const float* h    = (const float*)d_in[0];
    const float* x    = (const float*)d_in[1];
    const int*   ei   = (const int*)d_in[2];
    const float* ea   = (const float*)d_in[3];
    const float* w_e1 = (const float*)d_in[4];
    const float* b_e1 = (const float*)d_in[5];
    const float* w_e2 = (const float*)d_in[6];
    const float* b_e2 = (const float*)d_in[7];
    const float* w_f1 = (const float*)d_in[8];
    const float* b_f1 = (const float*)d_in[9];
    const float* w_f2 = (const float*)d_in[10];
    const float* b_f2 = (const float*)d_in[11];
    const float* w_c1 = (const float*)d_in[12];
    const float* b_c1 = (const float*)d_in[13];
    const float* w_c2 = (const float*)d_in[14];
    const float* smp  = (const float*)d_in[15];
    const float* omp  = (const float*)d_in[16];

    float* out   = (float*)d_out;
    float* agg   = out;
    float* out_x = out + (size_t)NB * NN * 64;

    char* ws = (char*)d_ws;
    int*   cnt_i = (int*)(ws + WS_CNT);
    int*   off   = (int*)(ws + WS_OFF);
    int*   cur   = (int*)(ws + WS_CUR);
    int*   part  = (int*)(ws + WS_PART);
    int4*  ecs   = (int4*)(ws + WS_ECS);
    short* pk    = (short*)(ws + WS_PK);
    short* hb16  = (short*)(ws + WS_HB);
    short* lins  = (short*)(ws + WS_LIN);

    hipMemsetAsync(cnt_i, 0, (size_t)NN * sizeof(int), stream);

    prep_kernel<<<PREP_CONV + PREP_PACK + PREP_HIST + PREP_ZERO, 256, 0, stream>>>(
        h, hb16, w_e1, w_e2, w_c1, w_f1, w_f2, pk, ei, cnt_i, out);
    scanA<<<NPART, 256, 0, stream>>>(cnt_i, part);
    scanB<<<1, 256, 0, stream>>>(part);
    scanC<<<NPART, 256, 0, stream>>>(cnt_i, part, off, cur);
    scatter_kernel<<<(EE + 255) / 256, 256, 0, stream>>>(ei, x, smp, omp, cur, ecs, lins);

    edge_kernel<<<EDGE_BLOCKS, 256, 0, stream>>>(
        hb16, ea, ecs, lins, b_e1, b_e2, b_c1, w_c2, pk, agg, out_x);

    const int node_waves = NB * ((NN + 31) / 32);     // 3126
    const int node_blocks = (node_waves + 3) / 4;     // 782
    node_kernel<<<node_blocks, 256, 0, stream>>>(
        hb16, x, b_f1, b_f2, pk, off, agg, out_x);
}

// Round 16
// 332.040 us; speedup vs baseline: 2.1514x; 2.1514x over previous
//
#include <hip/hip_runtime.h>
#include <hip/hip_bf16.h>
#include <cstdint>
#include <cstddef>

#define NN 50000     // nodes
#define EE 1000000   // edges
#define NB 2         // batch
#define OUT_ELEMS (NB * NN * 64 + NB * NN * 4)   // 6,800,000 floats

#define MSTR 72      // tile stride (shorts): 144 B rows; cols 0..63 = m, 64..71 spare
#define TILE (32 * MSTR)   // one batch m-tile, shorts (2304)

// packed-weight layout (shorts): B-fragment order [kstep][ntile][lane][8]
#define P_E1 0
#define P_E2 10240
#define P_C1 14336
#define P_F1 18432
#define P_F2 26624
#define E1_MAIN_SHORTS 8192      // e1 s=0..3 staged to LDS (16,384 B)

// d_ws byte offsets
#define WS_CNT   0            // int[NN]
#define WS_OFF   200704       // int[NN+1]
#define WS_CUR   401408       // int[NN]
#define WS_PART  602112       // int[256] scan partials
#define WS_ECS   603136       // int4[EE]  (16 MB)
#define WS_PK    16603136     // short[30720]
#define WS_HB    16664576     // short[NB*NN*64]  (12.8 MB)
#define WS_LIN   29464576     // short8[EE] lin streams (16 MB)

#define NPART 196             // scan blocks: 196*256 >= NN

typedef __attribute__((ext_vector_type(8))) short short8;
typedef __attribute__((ext_vector_type(4))) float f32x4;

__device__ __forceinline__ float fast_rcp(float v) { return __builtin_amdgcn_rcpf(v); }
__device__ __forceinline__ float silu_f(float v) { return v * fast_rcp(1.0f + __expf(-v)); }
__device__ __forceinline__ float ssgn_f(float v) { return v * fast_rcp(1.0f + fabsf(v)); }

__device__ __forceinline__ short f2bf(float f) {
    __hip_bfloat16 h = __float2bfloat16(f);
    return *reinterpret_cast<short*>(&h);
}
__device__ __forceinline__ float bf2f(short s) {
    union { unsigned u; float f; } c; c.u = ((unsigned)(unsigned short)s) << 16; return c.f;
}
__device__ __forceinline__ short8 pack8(float4 a, float4 b) {
    short8 r;
    r[0] = f2bf(a.x); r[1] = f2bf(a.y); r[2] = f2bf(a.z); r[3] = f2bf(a.w);
    r[4] = f2bf(b.x); r[5] = f2bf(b.y); r[6] = f2bf(b.z); r[7] = f2bf(b.w);
    return r;
}

// ---------------------------------------------------------------------------
// Fused prep: conv_h | pack_weights | hist | zero d_out
// ---------------------------------------------------------------------------
#define PREP_CONV 3125
#define PREP_PACK 15
#define PREP_HIST 3907
#define PREP_ZERO 3321

__global__ void prep_kernel(const float* __restrict__ h, short* __restrict__ hb16,
                            const float* __restrict__ w_e1, const float* __restrict__ w_e2,
                            const float* __restrict__ w_c1, const float* __restrict__ w_f1,
                            const float* __restrict__ w_f2, short* __restrict__ pk,
                            const int* __restrict__ ei, int* __restrict__ cnt_i,
                            float* __restrict__ out)
{
    const int bid = blockIdx.x;
    if (bid < PREP_CONV) {
        size_t i = ((size_t)bid * 256 + threadIdx.x) * 8;
        float4 lo = *reinterpret_cast<const float4*>(h + i);
        float4 hi = *reinterpret_cast<const float4*>(h + i + 4);
        *reinterpret_cast<short8*>(hb16 + i) = pack8(lo, hi);
    } else if (bid < PREP_CONV + PREP_PACK) {
        int g = (bid - PREP_CONV) * 256 + threadIdx.x;
        const int G_E1 = 5 * 4 * 64, G_E2 = 2 * 4 * 64, G_C1 = 2 * 4 * 64;
        const int G_F1 = 4 * 4 * 64, G_F2 = 2 * 4 * 64;
        if (g >= G_E1 + G_E2 + G_C1 + G_F1 + G_F2) return;
        const float* W; int loc; int mat;
        if (g < G_E1)                        { W = w_e1; loc = g;                         mat = 0; }
        else if (g < G_E1+G_E2)              { W = w_e2; loc = g - G_E1;                  mat = 1; }
        else if (g < G_E1+G_E2+G_C1)         { W = w_c1; loc = g - G_E1 - G_E2;           mat = 2; }
        else if (g < G_E1+G_E2+G_C1+G_F1)    { W = w_f1; loc = g - G_E1 - G_E2 - G_C1;    mat = 3; }
        else                                 { W = w_f2; loc = g - G_E1-G_E2-G_C1-G_F1;   mat = 4; }
        int l = loc & 63, n = (loc >> 6) & 3, s = loc >> 8;
        short8 out8;
        #pragma unroll
        for (int j = 0; j < 8; j++) {
            int kp = s * 32 + ((l >> 4) * 8) + j;
            int ko; bool valid;
            if (mat == 0) {
                if (kp < 128)      { ko = kp;     valid = true; }
                else if (kp < 144) { ko = kp + 1; valid = true; }   // ea rows (orig 129..144)
                else if (kp == 144){ ko = 128;    valid = true; }   // radial row
                else               { ko = 0;      valid = false; }
            } else if (mat == 3) { ko = kp; valid = kp < 128; }
            else                 { ko = kp; valid = kp < 64; }
            float v = valid ? W[ko * 64 + (n * 16 + (l & 15))] : 0.0f;
            out8[j] = f2bf(v);
        }
        *reinterpret_cast<short8*>(pk + (size_t)g * 8) = out8;
    } else if (bid < PREP_CONV + PREP_PACK + PREP_HIST) {
        int e = (bid - PREP_CONV - PREP_PACK) * 256 + threadIdx.x;
        if (e < EE) atomicAdd(&cnt_i[ei[e]], 1);
    } else {
        size_t i = ((size_t)(bid - PREP_CONV - PREP_PACK - PREP_HIST) * 256 + threadIdx.x) * 8;
        if (i < OUT_ELEMS) {
            float4 z = float4{0, 0, 0, 0};
            *reinterpret_cast<float4*>(out + i)     = z;
            *reinterpret_cast<float4*>(out + i + 4) = z;
        }
    }
}

// ---------------------------------------------------------------------------
// Multi-block exclusive scan of cnt -> off/cur
// ---------------------------------------------------------------------------
__global__ void scanA(const int* __restrict__ cnt_i, int* __restrict__ part) {
    int i = blockIdx.x * 256 + threadIdx.x;
    int v = (i < NN) ? cnt_i[i] : 0;
    #pragma unroll
    for (int d = 1; d < 64; d <<= 1) v += __shfl_xor(v, d);
    __shared__ int red[4];
    if ((threadIdx.x & 63) == 0) red[threadIdx.x >> 6] = v;
    __syncthreads();
    if (threadIdx.x == 0) part[blockIdx.x] = red[0] + red[1] + red[2] + red[3];
}

__global__ void scanB(int* __restrict__ part) {
    __shared__ int s[256];
    int t = threadIdx.x;
    int v = (t < NPART) ? part[t] : 0;
    s[t] = v;
    __syncthreads();
    for (int d = 1; d < 256; d <<= 1) {
        int u = (t >= d) ? s[t - d] : 0;
        __syncthreads();
        s[t] += u;
        __syncthreads();
    }
    if (t < NPART) part[t] = s[t] - v;   // exclusive
}

__global__ void scanC(const int* __restrict__ cnt_i, const int* __restrict__ part,
                      int* __restrict__ off, int* __restrict__ cur) {
    __shared__ int s[256];
    int i = blockIdx.x * 256 + threadIdx.x;
    int t = threadIdx.x;
    int v = (i < NN) ? cnt_i[i] : 0;
    s[t] = v;
    __syncthreads();
    for (int d = 1; d < 256; d <<= 1) {
        int u = (t >= d) ? s[t - d] : 0;
        __syncthreads();
        s[t] += u;
        __syncthreads();
    }
    int excl = s[t] - v + part[blockIdx.x];
    if (i < NN) { off[i] = excl; cur[i] = excl; }
    if (i == 0) off[NN] = EE;
}

// ---------------------------------------------------------------------------
// scatter: emits {eid,row,col,radpair} + lin streams per sorted position.
// ---------------------------------------------------------------------------
__global__ void scatter_kernel(const int* __restrict__ ei, const float* __restrict__ x,
                               const float* __restrict__ sm_p, const float* __restrict__ om_p,
                               int* __restrict__ cur, int4* __restrict__ ecs,
                               short* __restrict__ lins) {
    int e = blockIdx.x * 256 + threadIdx.x;
    if (e >= EE) return;
    int r = ei[e], c = ei[EE + e];
    int p = atomicAdd(&cur[r], 1);
    const float smv = sm_p[0], omv = om_p[0];
    short rp[2];
    short8 lv;
    #pragma unroll
    for (int b = 0; b < 2; b++) {
        float4 xr = *reinterpret_cast<const float4*>(x + ((size_t)b * NN + r) * 4);
        float4 xc = *reinterpret_cast<const float4*>(x + ((size_t)b * NN + c) * 4);
        float d0 = xr.x - xc.x, d1 = xr.y - xc.y, d2 = xr.z - xc.z, d3 = xr.w - xc.w;
        rp[b] = f2bf(d1 * d1 + d2 * d2 + d3 * d3 - d0 * d0);
        lv[b * 4 + 0] = f2bf(smv * xr.x + omv * xc.x);
        lv[b * 4 + 1] = f2bf(smv * xr.y + omv * xc.y);
        lv[b * 4 + 2] = f2bf(smv * xr.z + omv * xc.z);
        lv[b * 4 + 3] = f2bf(smv * xr.w + omv * xc.w);
    }
    int radpair = (int)(unsigned short)rp[0] | ((int)(unsigned short)rp[1] << 16);
    ecs[p] = make_int4(e, r, c, radpair);
    *reinterpret_cast<short8*>(lins + (size_t)p * 8) = lv;
}

// ---------------------------------------------------------------------------
// Edge kernel (r14 structure): 32 sorted edges x both batches per wave;
// e1 main weights staged to LDS; no x reads. 53,248 B LDS -> 3 blocks/CU.
// ---------------------------------------------------------------------------
__global__ __launch_bounds__(256, 3) void edge_kernel(
    const short* __restrict__ hb16,
    const float* __restrict__ ea, const int4* __restrict__ ecs,
    const short* __restrict__ lins,
    const float* __restrict__ b_e1, const float* __restrict__ b_e2,
    const float* __restrict__ b_c1, const float* __restrict__ w_c2,
    const short* __restrict__ pk,
    float* __restrict__ agg, float* __restrict__ xagg)
{
    __shared__ short wlds[E1_MAIN_SHORTS];   // 16,384 B: e1 s=0..3 B-frags
    __shared__ short smem[4][2 * TILE];      // 36,864 B (4 waves x 2 batch tiles)
    const int wid  = threadIdx.x >> 6;
    const int lane = threadIdx.x & 63;
    short* sm  = smem[wid];
    float* smf = reinterpret_cast<float*>(sm);

    // ---- stage e1 main weights to LDS (whole block, before any exit) ----
    {
        short8* dst = reinterpret_cast<short8*>(wlds);
        const short8* src = reinterpret_cast<const short8*>(pk);
        #pragma unroll
        for (int i = 0; i < E1_MAIN_SHORTS / 8 / 256; i++)   // 4 iters
            dst[i * 256 + threadIdx.x] = src[i * 256 + threadIdx.x];
    }
    __syncthreads();

    // bijective XCD swizzle (m204)
    const int nwg = gridDim.x;
    const int q = nwg >> 3, r_ = nwg & 7;
    const int xcd = blockIdx.x & 7, kk = blockIdx.x >> 3;
    const int bswz = (xcd < r_ ? xcd * (q + 1) : r_ * (q + 1) + (xcd - r_) * q) + kk;

    const int WPB = EE / 32;               // 31250 edge windows
    const int gw = bswz * 4 + wid;
    if (gw >= WPB) return;                 // after the only barrier: safe
    const int i0 = gw * 32;

    const int l15 = lane & 15;
    const int gq  = lane >> 4;
    const int kg  = gq * 8;

    // per-edge scalars on lanes 0..31 (shared across batches)
    int eid = 0, row = 0, col = 0, radpair = 0;
    short8 lv = short8{0, 0, 0, 0, 0, 0, 0, 0};
    if (lane < 32) {
        int4 ec = ecs[i0 + lane];          // coalesced 16B
        eid = ec.x; row = ec.y; col = ec.z; radpair = ec.w;
        lv = *reinterpret_cast<const short8*>(lins + (size_t)(i0 + lane) * 8);
    }

    int rowm[2], colm[2], eidm[2], radpm[2];
    #pragma unroll
    for (int m = 0; m < 2; m++) {
        int src = m * 16 + l15;            // < 32
        rowm[m] = __shfl(row, src);
        colm[m] = __shfl(col, src);
        eidm[m] = __shfl(eid, src);
        radpm[m] = __shfl(radpair, src);
    }
    const short* hbb[2] = { hb16, hb16 + (size_t)NN * 64 };
    const short8* pke1L = reinterpret_cast<const short8*>(wlds);       // s=0..3 (LDS)
    const short8* pke1G = reinterpret_cast<const short8*>(pk + P_E1);  // s=4 tail (global)
    const short8* pke2  = reinterpret_cast<const short8*>(pk + P_E2);
    const short8* pkc1  = reinterpret_cast<const short8*>(pk + P_C1);

    // ---- tail fragments (ea random + radial from stream), both batches ----
    short8 tail[2][2];
    #pragma unroll
    for (int b = 0; b < 2; b++)
        #pragma unroll
        for (int m = 0; m < 2; m++) {
            short8 v = short8{0, 0, 0, 0, 0, 0, 0, 0};
            if (gq < 2) {
                const float* src = ea + ((size_t)b * EE + eidm[m]) * 16 + gq * 8;
                float4 lo = *reinterpret_cast<const float4*>(src);
                float4 hi = *reinterpret_cast<const float4*>(src + 4);
                v = pack8(lo, hi);
            } else if (gq == 2) {
                v[0] = (short)((b == 0) ? (radpm[m] & 0xffff) : ((unsigned)radpm[m] >> 16));
            }
            tail[b][m] = v;
        }

    // ---- GEMM1: acc[b][m][n] (batch-paired) ----
    f32x4 acc[2][2][4];
    #pragma unroll
    for (int n = 0; n < 4; n++) {
        float bias = b_e1[n * 16 + l15];
        #pragma unroll
        for (int b = 0; b < 2; b++)
            #pragma unroll
            for (int m = 0; m < 2; m++) acc[b][m][n] = f32x4{bias, bias, bias, bias};
    }
    // tail first (global B-frags)
    __builtin_amdgcn_s_setprio(1);
    #pragma unroll
    for (int n = 0; n < 4; n++) {
        short8 bfr = pke1G[(4 * 4 + n) * 64 + lane];
        #pragma unroll
        for (int b = 0; b < 2; b++)
            #pragma unroll
            for (int m = 0; m < 2; m++)
                acc[b][m][n] = __builtin_amdgcn_mfma_f32_16x16x32_bf16(tail[b][m], bfr, acc[b][m][n], 0, 0, 0);
    }
    __builtin_amdgcn_s_setprio(0);
    // h rows (run-repeated; B-frags from LDS)
    #pragma unroll
    for (int s = 0; s < 2; s++) {
        short8 afr[2][2];
        #pragma unroll
        for (int b = 0; b < 2; b++)
            #pragma unroll
            for (int m = 0; m < 2; m++)
                afr[b][m] = *reinterpret_cast<const short8*>(
                    hbb[b] + (size_t)rowm[m] * 64 + s * 32 + kg);
        __builtin_amdgcn_s_setprio(1);
        #pragma unroll
        for (int n = 0; n < 4; n++) {
            short8 bfr = pke1L[(s * 4 + n) * 64 + lane];
            #pragma unroll
            for (int b = 0; b < 2; b++)
                #pragma unroll
                for (int m = 0; m < 2; m++)
                    acc[b][m][n] = __builtin_amdgcn_mfma_f32_16x16x32_bf16(afr[b][m], bfr, acc[b][m][n], 0, 0, 0);
        }
        __builtin_amdgcn_s_setprio(0);
    }
    // h cols (random gathers; B-frags from LDS)
    #pragma unroll
    for (int s2 = 0; s2 < 2; s2++) {
        short8 afr[2][2];
        #pragma unroll
        for (int b = 0; b < 2; b++)
            #pragma unroll
            for (int m = 0; m < 2; m++)
                afr[b][m] = *reinterpret_cast<const short8*>(
                    hbb[b] + (size_t)colm[m] * 64 + s2 * 32 + kg);
        __builtin_amdgcn_s_setprio(1);
        #pragma unroll
        for (int n = 0; n < 4; n++) {
            short8 bfr = pke1L[((2 + s2) * 4 + n) * 64 + lane];
            #pragma unroll
            for (int b = 0; b < 2; b++)
                #pragma unroll
                for (int m = 0; m < 2; m++)
                    acc[b][m][n] = __builtin_amdgcn_mfma_f32_16x16x32_bf16(afr[b][m], bfr, acc[b][m][n], 0, 0, 0);
        }
        __builtin_amdgcn_s_setprio(0);
    }

    // ---- t1 = silu(acc) -> LDS (both batch tiles) ----
    #pragma unroll
    for (int b = 0; b < 2; b++)
        #pragma unroll
        for (int m = 0; m < 2; m++)
            #pragma unroll
            for (int n = 0; n < 4; n++)
                #pragma unroll
                for (int r = 0; r < 4; r++)
                    sm[b * TILE + (m * 16 + gq * 4 + r) * MSTR + n * 16 + l15] =
                        f2bf(silu_f(acc[b][m][n][r]));
    asm volatile("s_waitcnt lgkmcnt(0)" ::: "memory");

    // ---- GEMM2 ----
    f32x4 acc2[2][2][4];
    #pragma unroll
    for (int n = 0; n < 4; n++) {
        float bias = b_e2[n * 16 + l15];
        #pragma unroll
        for (int b = 0; b < 2; b++)
            #pragma unroll
            for (int m = 0; m < 2; m++) acc2[b][m][n] = f32x4{bias, bias, bias, bias};
    }
    #pragma unroll
    for (int s = 0; s < 2; s++) {
        short8 afr[2][2];
        #pragma unroll
        for (int b = 0; b < 2; b++)
            #pragma unroll
            for (int m = 0; m < 2; m++)
                afr[b][m] = *reinterpret_cast<const short8*>(
                    sm + b * TILE + (m * 16 + l15) * MSTR + s * 32 + kg);
        __builtin_amdgcn_s_setprio(1);
        #pragma unroll
        for (int n = 0; n < 4; n++) {
            short8 bfr = pke2[(s * 4 + n) * 64 + lane];
            #pragma unroll
            for (int b = 0; b < 2; b++)
                #pragma unroll
                for (int m = 0; m < 2; m++)
                    acc2[b][m][n] = __builtin_amdgcn_mfma_f32_16x16x32_bf16(afr[b][m], bfr, acc2[b][m][n], 0, 0, 0);
        }
        __builtin_amdgcn_s_setprio(0);
    }
    asm volatile("s_waitcnt lgkmcnt(0)" ::: "memory");

    // ---- m = softsign(acc2) -> LDS ----
    #pragma unroll
    for (int b = 0; b < 2; b++)
        #pragma unroll
        for (int m = 0; m < 2; m++)
            #pragma unroll
            for (int n = 0; n < 4; n++)
                #pragma unroll
                for (int r = 0; r < 4; r++)
                    sm[b * TILE + (m * 16 + gq * 4 + r) * MSTR + n * 16 + l15] =
                        f2bf(ssgn_f(acc2[b][m][n][r]));
    asm volatile("s_waitcnt lgkmcnt(0)" ::: "memory");

    // ---- GEMM3 + phi ----
    f32x4 acc3[2][2][4];
    #pragma unroll
    for (int n = 0; n < 4; n++) {
        float bias = b_c1[n * 16 + l15];
        #pragma unroll
        for (int b = 0; b < 2; b++)
            #pragma unroll
            for (int m = 0; m < 2; m++) acc3[b][m][n] = f32x4{bias, bias, bias, bias};
    }
    #pragma unroll
    for (int s = 0; s < 2; s++) {
        short8 afr[2][2];
        #pragma unroll
        for (int b = 0; b < 2; b++)
            #pragma unroll
            for (int m = 0; m < 2; m++)
                afr[b][m] = *reinterpret_cast<const short8*>(
                    sm + b * TILE + (m * 16 + l15) * MSTR + s * 32 + kg);
        __builtin_amdgcn_s_setprio(1);
        #pragma unroll
        for (int n = 0; n < 4; n++) {
            short8 bfr = pkc1[(s * 4 + n) * 64 + lane];
            #pragma unroll
            for (int b = 0; b < 2; b++)
                #pragma unroll
                for (int m = 0; m < 2; m++)
                    acc3[b][m][n] = __builtin_amdgcn_mfma_f32_16x16x32_bf16(afr[b][m], bfr, acc3[b][m][n], 0, 0, 0);
        }
        __builtin_amdgcn_s_setprio(0);
    }
    float wc2v[4];
    #pragma unroll
    for (int n = 0; n < 4; n++) wc2v[n] = w_c2[n * 16 + l15];
    #pragma unroll
    for (int b = 0; b < 2; b++)
        #pragma unroll
        for (int m = 0; m < 2; m++)
            #pragma unroll
            for (int r = 0; r < 4; r++) {
                float v = 0.0f;
                #pragma unroll
                for (int n = 0; n < 4; n++) v = fmaf(silu_f(acc3[b][m][n][r]), wc2v[n], v);
                v += __shfl_xor(v, 1); v += __shfl_xor(v, 2);
                v += __shfl_xor(v, 4); v += __shfl_xor(v, 8);
                if (l15 == 0) smf[b * (TILE / 2) + (m * 16 + gq * 4 + r) * 36 + 32] = v;
            }
    asm volatile("s_waitcnt lgkmcnt(0)" ::: "memory");

    // ---- weighted coordinates = lin (from stream) * phi ----
    if (lane < 32) {
        float phi0 = smf[lane * 36 + 32];
        float phi1 = smf[(TILE / 2) + lane * 36 + 32];
        float4 wv0, wv1;
        wv0.x = bf2f(lv[0]) * phi0; wv0.y = bf2f(lv[1]) * phi0;
        wv0.z = bf2f(lv[2]) * phi0; wv0.w = bf2f(lv[3]) * phi0;
        wv1.x = bf2f(lv[4]) * phi1; wv1.y = bf2f(lv[5]) * phi1;
        wv1.z = bf2f(lv[6]) * phi1; wv1.w = bf2f(lv[7]) * phi1;
        *reinterpret_cast<float4*>(smf + lane * 36 + 32) = wv0;
        *reinterpret_cast<float4*>(smf + (TILE / 2) + lane * 36 + 32) = wv1;
    }
    asm volatile("s_waitcnt lgkmcnt(0)" ::: "memory");

    // ---- shared ballot run-merged scatter over 32 edges, both batches ----
    int nrow = __shfl_down(row, 1);
    unsigned long long bmask = __ballot((lane == 31) || (lane < 31 && row != nrow));
    float* aggb0 = agg;
    float* aggb1 = agg + (size_t)NN * 64;
    float* xb    = xagg + (size_t)((lane >> 2) & 1) * NN * 4;   // lanes 0-3 b0, 4-7 b1
    const int xsel = ((lane >> 2) & 1) * (TILE / 2) + (lane & 3);
    float mv0 = 0.0f, mv1 = 0.0f, xv = 0.0f;
    #pragma unroll
    for (int e = 0; e < 32; e++) {
        mv0 += bf2f(sm[e * MSTR + lane]);
        mv1 += bf2f(sm[TILE + e * MSTR + lane]);
        float t = smf[e * 36 + 32 + xsel];
        xv += (lane < 8) ? t : 0.0f;
        if ((bmask >> e) & 1ull) {
            int re = __shfl(row, e);
            atomicAdd(aggb0 + (size_t)re * 64 + lane, mv0);
            atomicAdd(aggb1 + (size_t)re * 64 + lane, mv1);
            if (lane < 8) atomicAdd(xb + (size_t)re * 4 + (lane & 3), xv);
            mv0 = 0.0f; mv1 = 0.0f; xv = 0.0f;
        }
    }
}

// ---------------------------------------------------------------------------
// Node kernel: M=32 tiles
// ---------------------------------------------------------------------------
__global__ __launch_bounds__(256, 4) void node_kernel(
    const short* __restrict__ hb16, const float* __restrict__ x,
    const float* __restrict__ b_f1, const float* __restrict__ b_f2,
    const short* __restrict__ pk,
    const int* __restrict__ off,
    float* out_h, float* out_x)
{
    __shared__ short smem[4][32 * MSTR];
    const int wid  = threadIdx.x >> 6;
    const int lane = threadIdx.x & 63;
    short* sm = smem[wid];

    const int WN = (NN + 31) / 32;   // 1563
    const int gw = blockIdx.x * 4 + wid;
    if (gw >= NB * WN) return;
    const int b  = gw / WN;
    const int n0 = (gw - b * WN) * 32;

    const int l15 = lane & 15;
    const int gq  = lane >> 4;
    const int kg  = gq * 8;

    const short* hbb  = hb16 + (size_t)b * NN * 64;
    const float* aggb = out_h + (size_t)b * NN * 64;

    f32x4 acc[2][4];
    #pragma unroll
    for (int n = 0; n < 4; n++) {
        float bias = b_f1[n * 16 + l15];
        #pragma unroll
        for (int m = 0; m < 2; m++) acc[m][n] = f32x4{bias, bias, bias, bias};
    }
    const short8* pkf1 = reinterpret_cast<const short8*>(pk + P_F1);
    #pragma unroll
    for (int s = 0; s < 4; s++) {
        short8 afr[2];
        #pragma unroll
        for (int m = 0; m < 2; m++) {
            int nd = n0 + m * 16 + l15;
            if (nd >= NN) nd = NN - 1;
            if (s < 2) {
                afr[m] = *reinterpret_cast<const short8*>(
                    hbb + (size_t)nd * 64 + s * 32 + kg);
            } else {
                const float* base = aggb + (size_t)nd * 64 + (s & 1) * 32 + kg;
                float4 lo = *reinterpret_cast<const float4*>(base);
                float4 hi = *reinterpret_cast<const float4*>(base + 4);
                afr[m] = pack8(lo, hi);
            }
        }
        __builtin_amdgcn_s_setprio(1);
        #pragma unroll
        for (int n = 0; n < 4; n++) {
            short8 bfr = pkf1[(s * 4 + n) * 64 + lane];
            #pragma unroll
            for (int m = 0; m < 2; m++)
                acc[m][n] = __builtin_amdgcn_mfma_f32_16x16x32_bf16(afr[m], bfr, acc[m][n], 0, 0, 0);
        }
        __builtin_amdgcn_s_setprio(0);
    }

    #pragma unroll
    for (int m = 0; m < 2; m++)
        #pragma unroll
        for (int n = 0; n < 4; n++)
            #pragma unroll
            for (int r = 0; r < 4; r++)
                sm[(m * 16 + gq * 4 + r) * MSTR + n * 16 + l15] = f2bf(silu_f(acc[m][n][r]));
    asm volatile("s_waitcnt lgkmcnt(0)" ::: "memory");

    f32x4 acc2[2][4];
    #pragma unroll
    for (int n = 0; n < 4; n++) {
        float bias = b_f2[n * 16 + l15];
        #pragma unroll
        for (int m = 0; m < 2; m++) acc2[m][n] = f32x4{bias, bias, bias, bias};
    }
    const short8* pkf2 = reinterpret_cast<const short8*>(pk + P_F2);
    #pragma unroll
    for (int s = 0; s < 2; s++) {
        short8 afr[2];
        #pragma unroll
        for (int m = 0; m < 2; m++)
            afr[m] = *reinterpret_cast<const short8*>(sm + (m * 16 + l15) * MSTR + s * 32 + kg);
        __builtin_amdgcn_s_setprio(1);
        #pragma unroll
        for (int n = 0; n < 4; n++) {
            short8 bfr = pkf2[(s * 4 + n) * 64 + lane];
            #pragma unroll
            for (int m = 0; m < 2; m++)
                acc2[m][n] = __builtin_amdgcn_mfma_f32_16x16x32_bf16(afr[m], bfr, acc2[m][n], 0, 0, 0);
        }
        __builtin_amdgcn_s_setprio(0);
    }

    float* ohb = out_h + (size_t)b * NN * 64;
    #pragma unroll
    for (int m = 0; m < 2; m++)
        #pragma unroll
        for (int r = 0; r < 4; r++) {
            int nd = n0 + m * 16 + gq * 4 + r;
            if (nd < NN) {
                #pragma unroll
                for (int n = 0; n < 4; n++)
                    ohb[(size_t)nd * 64 + n * 16 + l15] = ssgn_f(acc2[m][n][r]);
            }
        }

    const int node = n0 + lane;
    if (lane < 32 && node < NN) {
        int c_i = off[node + 1] - off[node];
        float c = (float)(c_i < 1 ? 1 : c_i);
        float invc = fast_rcp(c);
        const float4 xv = *reinterpret_cast<const float4*>(x + ((size_t)b * NN + node) * 4);
        float* xop = out_x + ((size_t)b * NN + node) * 4;
        float4 xa = *reinterpret_cast<float4*>(xop);
        float4 r;
        r.x = xv.x + xa.x * invc;
        r.y = xv.y + xa.y * invc;
        r.z = xv.z + xa.z * invc;
        r.w = xv.w + xa.w * invc;
        *reinterpret_cast<float4*>(xop) = r;
    }
}

// ---------------------------------------------------------------------------
extern "C" void kernel_launch(void* const* d_in, const int* in_sizes, int n_in,
                              void* d_out, int out_size, void* d_ws, size_t ws_size,
                              hipStream_t stream) {
    const float* h    = (const float*)d_in[0];
    const float* x    = (const float*)d_in[1];
    const int*   ei   = (const int*)d_in[2];
    const float* ea   = (const float*)d_in[3];
    const float* w_e1 = (const float*)d_in[4];
    const float* b_e1 = (const float*)d_in[5];
    const float* w_e2 = (const float*)d_in[6];
    const float* b_e2 = (const float*)d_in[7];
    const float* w_f1 = (const float*)d_in[8];
    const float* b_f1 = (const float*)d_in[9];
    const float* w_f2 = (const float*)d_in[10];
    const float* b_f2 = (const float*)d_in[11];
    const float* w_c1 = (const float*)d_in[12];
    const float* b_c1 = (const float*)d_in[13];
    const float* w_c2 = (const float*)d_in[14];
    const float* smp  = (const float*)d_in[15];
    const float* omp  = (const float*)d_in[16];

    float* out   = (float*)d_out;
    float* agg   = out;
    float* out_x = out + (size_t)NB * NN * 64;

    char* ws = (char*)d_ws;
    int*   cnt_i = (int*)(ws + WS_CNT);
    int*   off   = (int*)(ws + WS_OFF);
    int*   cur   = (int*)(ws + WS_CUR);
    int*   part  = (int*)(ws + WS_PART);
    int4*  ecs   = (int4*)(ws + WS_ECS);
    short* pk    = (short*)(ws + WS_PK);
    short* hb16  = (short*)(ws + WS_HB);
    short* lins  = (short*)(ws + WS_LIN);

    hipMemsetAsync(cnt_i, 0, (size_t)NN * sizeof(int), stream);

    prep_kernel<<<PREP_CONV + PREP_PACK + PREP_HIST + PREP_ZERO, 256, 0, stream>>>(
        h, hb16, w_e1, w_e2, w_c1, w_f1, w_f2, pk, ei, cnt_i, out);
    scanA<<<NPART, 256, 0, stream>>>(cnt_i, part);
    scanB<<<1, 256, 0, stream>>>(part);
    scanC<<<NPART, 256, 0, stream>>>(cnt_i, part, off, cur);
    scatter_kernel<<<(EE + 255) / 256, 256, 0, stream>>>(ei, x, smp, omp, cur, ecs, lins);

    const int edge_waves = EE / 32;                   // 31250 (batch-paired)
    const int edge_blocks = (edge_waves + 3) / 4;     // 7813
    edge_kernel<<<edge_blocks, 256, 0, stream>>>(
        hb16, ea, ecs, lins, b_e1, b_e2, b_c1, w_c2, pk, agg, out_x);

    const int node_waves = NB * ((NN + 31) / 32);     // 3126
    const int node_blocks = (node_waves + 3) / 4;     // 782
    node_kernel<<<node_blocks, 256, 0, stream>>>(
        hb16, x, b_f1, b_f2, pk, off, agg, out_x);
}